// Round 1
// baseline (577.738 us; speedup 1.0000x reference)
//
#include <hip/hip_runtime.h>
#include <math.h>

#define N_NODES 50000
#define N_EDGES 800000
#define ET (N_EDGES + N_NODES)   // 850000 incl. self-loops
#define KD 128                   // inner dim of both matmuls
#define Z 32

static __device__ __forceinline__ float lrelu(float x){ return x > 0.f ? x : 0.2f*x; }

// ---------- CSR build ----------
__global__ __launch_bounds__(256) void hist_kernel(const int* __restrict__ edges, int* __restrict__ deg){
  int k = blockIdx.x*256 + threadIdx.x;
  if(k >= ET) return;
  int d = (k < N_EDGES) ? edges[N_EDGES + k] : (k - N_EDGES);
  atomicAdd(&deg[d], 1);
}

__global__ __launch_bounds__(1024) void scan_kernel(const int* __restrict__ deg, int* __restrict__ rowptr, int* __restrict__ cursor){
  __shared__ int sums[1024];
  int tid = threadIdx.x;
  const int chunk = (N_NODES + 1023)/1024; // 49
  int begin = tid*chunk; int end = min(begin+chunk, N_NODES);
  int s = 0;
  for(int i=begin;i<end;i++) s += deg[i];
  sums[tid] = s;
  __syncthreads();
  for(int off=1; off<1024; off<<=1){
    int v = 0;
    if(tid >= off) v = sums[tid-off];
    __syncthreads();
    if(tid >= off) sums[tid] += v;
    __syncthreads();
  }
  int run = (tid>0) ? sums[tid-1] : 0;
  for(int i=begin;i<end;i++){
    rowptr[i] = run; cursor[i] = run; run += deg[i];
  }
  if(tid == 1023) rowptr[N_NODES] = sums[1023];
}

__global__ __launch_bounds__(256) void scatter_kernel(const int* __restrict__ edges, int* __restrict__ cursor, int* __restrict__ esrc){
  int k = blockIdx.x*256 + threadIdx.x;
  if(k >= ET) return;
  int s, d;
  if(k < N_EDGES){ s = edges[k]; d = edges[N_EDGES+k]; } else { s = d = k - N_EDGES; }
  int pos = atomicAdd(&cursor[d], 1);
  esrc[pos] = s;
}

// ---------- dense matmul: out[n][j] = sum_k X[n][k] * W[j][k] ----------
// W staged in LDS, XOR-swizzled at float4 granularity to spread banks.
// 256 threads = G col-groups x (256/G) row-groups; each thread: 4 rows x 4 cols.
template<int OC, int NR>
__global__ __launch_bounds__(256) void mm_kernel(const float* __restrict__ X,
                                                 const float* __restrict__ Wa,
                                                 const float* __restrict__ Wb, int splitRow,
                                                 float* __restrict__ out){
  constexpr int G  = OC/4;     // lanes in col dimension
  constexpr int RG = 256/G;    // row groups
  static_assert(NR == RG*4, "rows per block mismatch");
  __shared__ __align__(16) float Wl[OC*KD];

  for(int idx = threadIdx.x; idx < OC*KD; idx += 256){
    int j = idx >> 7;          // KD = 128
    int k = idx & 127;
    float v = (j < splitRow) ? Wa[j*KD + k] : Wb[(j-splitRow)*KD + k];
    int k4 = k >> 2, u = k & 3;
    Wl[j*KD + 4*(k4 ^ (j & 31)) + u] = v;
  }
  __syncthreads();

  int cx = threadIdx.x % G;
  int ry = threadIdx.x / G;
  int row0 = blockIdx.x * NR + ry*4;

  float acc[4][4];
  #pragma unroll
  for(int i=0;i<4;i++)
    #pragma unroll
    for(int j=0;j<4;j++) acc[i][j] = 0.f;

  for(int k4 = 0; k4 < KD/4; k4++){
    float4 xv[4];
    #pragma unroll
    for(int i=0;i<4;i++){
      int r = row0 + i; r = r < N_NODES ? r : N_NODES-1;
      xv[i] = *(const float4*)(X + (size_t)r*KD + 4*k4);
    }
    #pragma unroll
    for(int jj=0;jj<4;jj++){
      int c = cx + jj*G;
      float4 wv = *(const float4*)(&Wl[c*KD + 4*(k4 ^ (c & 31))]);
      #pragma unroll
      for(int i=0;i<4;i++){
        acc[i][jj] += xv[i].x*wv.x;
        acc[i][jj] += xv[i].y*wv.y;
        acc[i][jj] += xv[i].z*wv.z;
        acc[i][jj] += xv[i].w*wv.w;
      }
    }
  }

  #pragma unroll
  for(int i=0;i<4;i++){
    int r = row0 + i;
    if(r < N_NODES){
      #pragma unroll
      for(int jj=0;jj<4;jj++) out[(size_t)r*OC + cx + jj*G] = acc[i][jj];
    }
  }
}

// ---------- attention coefficient dots ----------
// layer1: xp [N,128] (2 heads x 64); as1/ad1 [N,2]
__global__ __launch_bounds__(256) void alpha1_kernel(const float* __restrict__ xp,
                                                     const float* __restrict__ asv, const float* __restrict__ adv,
                                                     float* __restrict__ as1, float* __restrict__ ad1){
  int node = blockIdx.x*4 + (threadIdx.x>>6);
  int l = threadIdx.x & 63;
  if(node >= N_NODES) return;
  float x0 = xp[(size_t)node*128 + l], x1 = xp[(size_t)node*128 + 64 + l];
  float s0 = x0*asv[l], s1 = x1*asv[64+l];
  float d0 = x0*adv[l], d1 = x1*adv[64+l];
  for(int off=32; off; off>>=1){
    s0 += __shfl_xor(s0, off); s1 += __shfl_xor(s1, off);
    d0 += __shfl_xor(d0, off); d1 += __shfl_xor(d1, off);
  }
  if(l == 0){ as1[node*2]=s0; as1[node*2+1]=s1; ad1[node*2]=d0; ad1[node*2+1]=d1; }
}

// layer2: xp2 [N,64] (cols 0..31 = mu, 32..63 = std); as2/ad2 [N,2] = [mu,std]
__global__ __launch_bounds__(256) void alpha2_kernel(const float* __restrict__ xp2,
                                                     const float* __restrict__ asmu, const float* __restrict__ admu,
                                                     const float* __restrict__ asst, const float* __restrict__ adst,
                                                     float* __restrict__ as2, float* __restrict__ ad2){
  int node = blockIdx.x*4 + (threadIdx.x>>6);
  int l = threadIdx.x & 63;
  if(node >= N_NODES) return;
  int half = l >> 5, c = l & 31;
  float v = xp2[(size_t)node*64 + l];
  float sp = v * (half ? asst[c] : asmu[c]);
  float dp = v * (half ? adst[c] : admu[c]);
  for(int off=16; off; off>>=1){ sp += __shfl_xor(sp, off); dp += __shfl_xor(dp, off); }
  if(c == 0){ as2[node*2+half] = sp; ad2[node*2+half] = dp; }
}

// ---------- edge aggregation, layer 1 (one wave per dst node) ----------
__global__ __launch_bounds__(256) void agg1_kernel(const int* __restrict__ rowptr, const int* __restrict__ esrc,
                                                   const float* __restrict__ xp, const float* __restrict__ as1,
                                                   const float* __restrict__ ad1, const float* __restrict__ b1,
                                                   float* __restrict__ h){
  int node = blockIdx.x*4 + (threadIdx.x>>6);
  int l = threadIdx.x & 63;
  if(node >= N_NODES) return;
  int beg = rowptr[node], end = rowptr[node+1];
  float adn0 = ad1[node*2], adn1 = ad1[node*2+1];
  // pass 1: segment max per head (lanes partition edges)
  float m0 = -3.4e38f, m1 = -3.4e38f;
  for(int i = beg + l; i < end; i += 64){
    int s = esrc[i];
    m0 = fmaxf(m0, lrelu(as1[s*2]   + adn0));
    m1 = fmaxf(m1, lrelu(as1[s*2+1] + adn1));
  }
  for(int off=32; off; off>>=1){ m0 = fmaxf(m0, __shfl_xor(m0, off)); m1 = fmaxf(m1, __shfl_xor(m1, off)); }
  // pass 2: exp-sum + weighted accumulate (uniform edge loop, lane = feature)
  float acc0=0.f, acc1=0.f, s0=0.f, s1=0.f;
  for(int i = beg; i < end; i++){
    int s = esrc[i];
    float w0 = __expf(lrelu(as1[s*2]   + adn0) - m0);
    float w1 = __expf(lrelu(as1[s*2+1] + adn1) - m1);
    s0 += w0; s1 += w1;
    acc0 += w0 * xp[(size_t)s*128 + l];
    acc1 += w1 * xp[(size_t)s*128 + 64 + l];
  }
  float r0 = acc0/s0 + b1[l];
  float r1 = acc1/s1 + b1[64+l];
  h[(size_t)node*128 + l]      = fmaxf(r0, 0.f);   // relu between layers
  h[(size_t)node*128 + 64 + l] = fmaxf(r1, 0.f);
}

// ---------- edge aggregation, layer 2 (mu+std fused; lanes 0..31 mu, 32..63 std) ----------
__global__ __launch_bounds__(256) void agg2_kernel(const int* __restrict__ rowptr, const int* __restrict__ esrc,
                                                   const float* __restrict__ xp2, const float* __restrict__ as2,
                                                   const float* __restrict__ ad2, const float* __restrict__ bmu,
                                                   const float* __restrict__ bst, float* __restrict__ out){
  int node = blockIdx.x*4 + (threadIdx.x>>6);
  int l = threadIdx.x & 63;
  if(node >= N_NODES) return;
  int half = l >> 5, c = l & 31;
  int beg = rowptr[node], end = rowptr[node+1];
  float adn = ad2[node*2 + half];
  float m = -3.4e38f;
  for(int i = beg + c; i < end; i += 32){      // each 32-lane half covers ALL edges
    int s = esrc[i];
    m = fmaxf(m, lrelu(as2[s*2+half] + adn));
  }
  for(int off=16; off; off>>=1) m = fmaxf(m, __shfl_xor(m, off));
  float acc = 0.f, ssum = 0.f;
  for(int i = beg; i < end; i++){
    int s = esrc[i];
    float w = __expf(lrelu(as2[s*2+half] + adn) - m);
    ssum += w;
    acc += w * xp2[(size_t)s*64 + l];
  }
  float r = acc/ssum + (half ? bst[c] : bmu[c]);
  out[(half ? (size_t)N_NODES*Z : 0) + (size_t)node*Z + c] = r;
}

extern "C" void kernel_launch(void* const* d_in, const int* in_sizes, int n_in,
                              void* d_out, int out_size, void* d_ws, size_t ws_size,
                              hipStream_t stream){
  const float* x    = (const float*)d_in[0];
  const int*   edges= (const int*)d_in[1];
  const float* W1   = (const float*)d_in[2];
  const float* as1v = (const float*)d_in[3];
  const float* ad1v = (const float*)d_in[4];
  const float* b1   = (const float*)d_in[5];
  const float* Wmu  = (const float*)d_in[6];
  const float* asmu = (const float*)d_in[7];
  const float* admu = (const float*)d_in[8];
  const float* bmu  = (const float*)d_in[9];
  const float* Wst  = (const float*)d_in[10];
  const float* asst = (const float*)d_in[11];
  const float* adst = (const float*)d_in[12];
  const float* bst  = (const float*)d_in[13];
  float* out = (float*)d_out;

  char* p = (char*)d_ws;
  auto alloc = [&](size_t bytes)->char*{ char* r = p; p += (bytes + 255) & ~size_t(255); return r; };
  int*   deg    = (int*)  alloc((size_t)N_NODES*4);
  int*   rowptr = (int*)  alloc((size_t)(N_NODES+1)*4);
  int*   cursor = (int*)  alloc((size_t)N_NODES*4);
  int*   esrc   = (int*)  alloc((size_t)ET*4);
  float* xp1    = (float*)alloc((size_t)N_NODES*128*4);
  float* as1    = (float*)alloc((size_t)N_NODES*2*4);
  float* ad1    = (float*)alloc((size_t)N_NODES*2*4);
  float* h      = (float*)alloc((size_t)N_NODES*128*4);
  float* xp2    = (float*)alloc((size_t)N_NODES*64*4);
  float* as2    = (float*)alloc((size_t)N_NODES*2*4);
  float* ad2    = (float*)alloc((size_t)N_NODES*2*4);

  hipMemsetAsync(deg, 0, (size_t)N_NODES*4, stream);
  hist_kernel   <<<(ET+255)/256, 256, 0, stream>>>(edges, deg);
  scan_kernel   <<<1, 1024, 0, stream>>>(deg, rowptr, cursor);
  scatter_kernel<<<(ET+255)/256, 256, 0, stream>>>(edges, cursor, esrc);

  mm_kernel<128,32><<<(N_NODES+31)/32, 256, 0, stream>>>(x, W1, W1, 128, xp1);
  alpha1_kernel<<<(N_NODES+3)/4, 256, 0, stream>>>(xp1, as1v, ad1v, as1, ad1);
  agg1_kernel  <<<(N_NODES+3)/4, 256, 0, stream>>>(rowptr, esrc, xp1, as1, ad1, b1, h);

  mm_kernel<64,64><<<(N_NODES+63)/64, 256, 0, stream>>>(h, Wmu, Wst, 32, xp2);
  alpha2_kernel<<<(N_NODES+3)/4, 256, 0, stream>>>(xp2, asmu, admu, asst, adst, as2, ad2);
  agg2_kernel  <<<(N_NODES+3)/4, 256, 0, stream>>>(rowptr, esrc, xp2, as2, ad2, bmu, bst, out);
}

// Round 2
// 475.611 us; speedup vs baseline: 1.2147x; 1.2147x over previous
//
#include <hip/hip_runtime.h>
#include <math.h>

#define N_NODES 50000
#define N_EDGES 800000
#define ET (N_EDGES + N_NODES)   // 850000 incl. self-loops
#define KD 128                   // inner dim of both matmuls
#define Z 32
#define NBS ((N_NODES + 1023) / 1024)   // 49 scan blocks

static __device__ __forceinline__ float lrelu(float x){ return x > 0.f ? x : 0.2f*x; }

// ---------- CSR build ----------
__global__ __launch_bounds__(256) void hist_kernel(const int* __restrict__ edges, int* __restrict__ deg){
  int k = blockIdx.x*256 + threadIdx.x;
  if(k >= ET) return;
  int d = (k < N_EDGES) ? edges[N_EDGES + k] : (k - N_EDGES);
  atomicAdd(&deg[d], 1);
}

// stage 1: per-block (1024 nodes) sums
__global__ __launch_bounds__(256) void scan1_kernel(const int* __restrict__ deg, int* __restrict__ bsum){
  int b = blockIdx.x, t = threadIdx.x;
  int base = b*1024 + t*4;
  int s = 0;
  #pragma unroll
  for(int i=0;i<4;i++){ int n = base+i; if(n < N_NODES) s += deg[n]; }
  for(int off=32; off; off>>=1) s += __shfl_xor(s, off);
  __shared__ int ws[4];
  if((t&63)==0) ws[t>>6] = s;
  __syncthreads();
  if(t==0) bsum[b] = ws[0]+ws[1]+ws[2]+ws[3];
}

// stage 2: exclusive scan of 49 block sums (one wave)
__global__ __launch_bounds__(64) void scan2_kernel(const int* __restrict__ bsum, int* __restrict__ bpre){
  int t = threadIdx.x;
  int x = (t < NBS) ? bsum[t] : 0;
  int v = x;
  for(int off=1; off<64; off<<=1){
    int u = __shfl_up(v, off);
    if(t >= off) v += u;
  }
  if(t < NBS) bpre[t] = v - x;
}

// stage 3: per-block prefix + global offset -> rowptr & cursor
__global__ __launch_bounds__(256) void scan3_kernel(const int* __restrict__ deg, const int* __restrict__ bpre,
                                                    int* __restrict__ rowptr, int* __restrict__ cursor){
  int b = blockIdx.x, t = threadIdx.x;
  int lane = t & 63, wv = t >> 6;
  int base = b*1024 + t*4;
  int d[4]; int s = 0;
  #pragma unroll
  for(int i=0;i<4;i++){ int n = base+i; d[i] = (n < N_NODES) ? deg[n] : 0; s += d[i]; }
  int v = s;
  for(int off=1; off<64; off<<=1){
    int u = __shfl_up(v, off);
    if(lane >= off) v += u;
  }
  int texcl = v - s;
  __shared__ int wtot[4];
  if(lane == 63) wtot[wv] = v;
  __syncthreads();
  int woff = 0;
  for(int i=0;i<wv;i++) woff += wtot[i];
  int run = bpre[b] + woff + texcl;
  #pragma unroll
  for(int i=0;i<4;i++){
    int n = base+i;
    if(n < N_NODES){ rowptr[n] = run; cursor[n] = run; run += d[i]; }
  }
  if(b == 0 && t == 0) rowptr[N_NODES] = ET;
}

__global__ __launch_bounds__(256) void scatter_kernel(const int* __restrict__ edges, int* __restrict__ cursor, int* __restrict__ esrc){
  int k = blockIdx.x*256 + threadIdx.x;
  if(k >= ET) return;
  int s, d;
  if(k < N_EDGES){ s = edges[k]; d = edges[N_EDGES+k]; } else { s = d = k - N_EDGES; }
  int pos = atomicAdd(&cursor[d], 1);
  esrc[pos] = s;
}

// ---------- dense matmul: out[n][j] = sum_k X[n][k] * W[j][k] ----------
template<int OC, int NR>
__global__ __launch_bounds__(256) void mm_kernel(const float* __restrict__ X,
                                                 const float* __restrict__ Wa,
                                                 const float* __restrict__ Wb, int splitRow,
                                                 float* __restrict__ out){
  constexpr int G  = OC/4;
  constexpr int RG = 256/G;
  static_assert(NR == RG*4, "rows per block mismatch");
  __shared__ __align__(16) float Wl[OC*KD];

  for(int idx = threadIdx.x; idx < OC*KD; idx += 256){
    int j = idx >> 7;
    int k = idx & 127;
    float v = (j < splitRow) ? Wa[j*KD + k] : Wb[(j-splitRow)*KD + k];
    int k4 = k >> 2, u = k & 3;
    Wl[j*KD + 4*(k4 ^ (j & 31)) + u] = v;
  }
  __syncthreads();

  int cx = threadIdx.x % G;
  int ry = threadIdx.x / G;
  int row0 = blockIdx.x * NR + ry*4;

  float acc[4][4];
  #pragma unroll
  for(int i=0;i<4;i++)
    #pragma unroll
    for(int j=0;j<4;j++) acc[i][j] = 0.f;

  for(int k4 = 0; k4 < KD/4; k4++){
    float4 xv[4];
    #pragma unroll
    for(int i=0;i<4;i++){
      int r = row0 + i; r = r < N_NODES ? r : N_NODES-1;
      xv[i] = *(const float4*)(X + (size_t)r*KD + 4*k4);
    }
    #pragma unroll
    for(int jj=0;jj<4;jj++){
      int c = cx + jj*G;
      float4 wv = *(const float4*)(&Wl[c*KD + 4*(k4 ^ (c & 31))]);
      #pragma unroll
      for(int i=0;i<4;i++){
        acc[i][jj] += xv[i].x*wv.x;
        acc[i][jj] += xv[i].y*wv.y;
        acc[i][jj] += xv[i].z*wv.z;
        acc[i][jj] += xv[i].w*wv.w;
      }
    }
  }

  #pragma unroll
  for(int i=0;i<4;i++){
    int r = row0 + i;
    if(r < N_NODES){
      #pragma unroll
      for(int jj=0;jj<4;jj++) out[(size_t)r*OC + cx + jj*G] = acc[i][jj];
    }
  }
}

// ---------- attention coefficient dots ----------
__global__ __launch_bounds__(256) void alpha1_kernel(const float* __restrict__ xp,
                                                     const float* __restrict__ asv, const float* __restrict__ adv,
                                                     float* __restrict__ as1, float* __restrict__ ad1){
  int node = blockIdx.x*4 + (threadIdx.x>>6);
  int l = threadIdx.x & 63;
  if(node >= N_NODES) return;
  float x0 = xp[(size_t)node*128 + l], x1 = xp[(size_t)node*128 + 64 + l];
  float s0 = x0*asv[l], s1 = x1*asv[64+l];
  float d0 = x0*adv[l], d1 = x1*adv[64+l];
  for(int off=32; off; off>>=1){
    s0 += __shfl_xor(s0, off); s1 += __shfl_xor(s1, off);
    d0 += __shfl_xor(d0, off); d1 += __shfl_xor(d1, off);
  }
  if(l == 0){ as1[node*2]=s0; as1[node*2+1]=s1; ad1[node*2]=d0; ad1[node*2+1]=d1; }
}

__global__ __launch_bounds__(256) void alpha2_kernel(const float* __restrict__ xp2,
                                                     const float* __restrict__ asmu, const float* __restrict__ admu,
                                                     const float* __restrict__ asst, const float* __restrict__ adst,
                                                     float* __restrict__ as2, float* __restrict__ ad2){
  int node = blockIdx.x*4 + (threadIdx.x>>6);
  int l = threadIdx.x & 63;
  if(node >= N_NODES) return;
  int half = l >> 5, c = l & 31;
  float v = xp2[(size_t)node*64 + l];
  float sp = v * (half ? asst[c] : asmu[c]);
  float dp = v * (half ? adst[c] : admu[c]);
  for(int off=16; off; off>>=1){ sp += __shfl_xor(sp, off); dp += __shfl_xor(dp, off); }
  if(c == 0){ as2[node*2+half] = sp; ad2[node*2+half] = dp; }
}

// ---------- edge aggregation, layer 1 (one wave per dst node; float2 lanes) ----------
__global__ __launch_bounds__(256) void agg1_kernel(const int* __restrict__ rowptr, const int* __restrict__ esrc,
                                                   const float* __restrict__ xp, const float* __restrict__ as1,
                                                   const float* __restrict__ ad1, const float* __restrict__ b1,
                                                   float* __restrict__ h){
  int node = blockIdx.x*4 + (threadIdx.x>>6);
  int l = threadIdx.x & 63;
  if(node >= N_NODES) return;
  int beg = rowptr[node], end = rowptr[node+1];
  const float2* as1p = (const float2*)as1;
  float2 adn = ((const float2*)ad1)[node];
  // pass 1: segment max per head (lanes partition edges)
  float m0 = -3.4e38f, m1 = -3.4e38f;
  for(int i = beg + l; i < end; i += 64){
    float2 a = as1p[esrc[i]];
    m0 = fmaxf(m0, lrelu(a.x + adn.x));
    m1 = fmaxf(m1, lrelu(a.y + adn.y));
  }
  for(int off=32; off; off>>=1){ m0 = fmaxf(m0, __shfl_xor(m0, off)); m1 = fmaxf(m1, __shfl_xor(m1, off)); }
  // pass 2: exp-sum + weighted accumulate; lane l holds features 2l, 2l+1
  const float2* xpv = (const float2*)xp;
  float accx = 0.f, accy = 0.f, s0 = 0.f, s1 = 0.f;
  for(int i = beg; i < end; i++){
    int s = esrc[i];
    float2 a = as1p[s];
    float w0 = __expf(lrelu(a.x + adn.x) - m0);
    float w1 = __expf(lrelu(a.y + adn.y) - m1);
    s0 += w0; s1 += w1;
    float2 xv = xpv[(size_t)s*64 + l];
    float w = (l < 32) ? w0 : w1;
    accx += w * xv.x;
    accy += w * xv.y;
  }
  float sd = (l < 32) ? s0 : s1;
  float2 bb = ((const float2*)b1)[l];
  float2 r;
  r.x = fmaxf(accx/sd + bb.x, 0.f);
  r.y = fmaxf(accy/sd + bb.y, 0.f);
  ((float2*)h)[(size_t)node*64 + l] = r;
}

// ---------- edge aggregation, layer 2 (mu+std fused; lanes 0..31 mu, 32..63 std) ----------
__global__ __launch_bounds__(256) void agg2_kernel(const int* __restrict__ rowptr, const int* __restrict__ esrc,
                                                   const float* __restrict__ xp2, const float* __restrict__ as2,
                                                   const float* __restrict__ ad2, const float* __restrict__ bmu,
                                                   const float* __restrict__ bst, float* __restrict__ out){
  int node = blockIdx.x*4 + (threadIdx.x>>6);
  int l = threadIdx.x & 63;
  if(node >= N_NODES) return;
  int half = l >> 5, c = l & 31;
  int beg = rowptr[node], end = rowptr[node+1];
  const float2* as2p = (const float2*)as2;
  float2 adn2 = ((const float2*)ad2)[node];
  float adn = half ? adn2.y : adn2.x;
  float m = -3.4e38f;
  for(int i = beg + c; i < end; i += 32){
    float2 a = as2p[esrc[i]];
    m = fmaxf(m, lrelu((half ? a.y : a.x) + adn));
  }
  for(int off=16; off; off>>=1) m = fmaxf(m, __shfl_xor(m, off));
  float acc = 0.f, ssum = 0.f;
  for(int i = beg; i < end; i++){
    int s = esrc[i];
    float2 a = as2p[s];
    float w = __expf(lrelu((half ? a.y : a.x) + adn) - m);
    ssum += w;
    acc += w * xp2[(size_t)s*64 + l];
  }
  float r = acc/ssum + (half ? bst[c] : bmu[c]);
  out[(half ? (size_t)N_NODES*Z : 0) + (size_t)node*Z + c] = r;
}

extern "C" void kernel_launch(void* const* d_in, const int* in_sizes, int n_in,
                              void* d_out, int out_size, void* d_ws, size_t ws_size,
                              hipStream_t stream){
  const float* x    = (const float*)d_in[0];
  const int*   edges= (const int*)d_in[1];
  const float* W1   = (const float*)d_in[2];
  const float* as1v = (const float*)d_in[3];
  const float* ad1v = (const float*)d_in[4];
  const float* b1   = (const float*)d_in[5];
  const float* Wmu  = (const float*)d_in[6];
  const float* asmu = (const float*)d_in[7];
  const float* admu = (const float*)d_in[8];
  const float* bmu  = (const float*)d_in[9];
  const float* Wst  = (const float*)d_in[10];
  const float* asst = (const float*)d_in[11];
  const float* adst = (const float*)d_in[12];
  const float* bst  = (const float*)d_in[13];
  float* out = (float*)d_out;

  char* p = (char*)d_ws;
  auto alloc = [&](size_t bytes)->char*{ char* r = p; p += (bytes + 255) & ~size_t(255); return r; };
  int*   deg    = (int*)  alloc((size_t)N_NODES*4);
  int*   rowptr = (int*)  alloc((size_t)(N_NODES+1)*4);
  int*   cursor = (int*)  alloc((size_t)N_NODES*4);
  int*   esrc   = (int*)  alloc((size_t)ET*4);
  int*   bsum   = (int*)  alloc((size_t)NBS*4);
  int*   bpre   = (int*)  alloc((size_t)NBS*4);
  float* xp1    = (float*)alloc((size_t)N_NODES*128*4);
  float* as1    = (float*)alloc((size_t)N_NODES*2*4);
  float* ad1    = (float*)alloc((size_t)N_NODES*2*4);
  float* h      = (float*)alloc((size_t)N_NODES*128*4);
  float* xp2    = (float*)alloc((size_t)N_NODES*64*4);
  float* as2    = (float*)alloc((size_t)N_NODES*2*4);
  float* ad2    = (float*)alloc((size_t)N_NODES*2*4);

  hipMemsetAsync(deg, 0, (size_t)N_NODES*4, stream);
  hist_kernel   <<<(ET+255)/256, 256, 0, stream>>>(edges, deg);
  scan1_kernel  <<<NBS, 256, 0, stream>>>(deg, bsum);
  scan2_kernel  <<<1, 64, 0, stream>>>(bsum, bpre);
  scan3_kernel  <<<NBS, 256, 0, stream>>>(deg, bpre, rowptr, cursor);
  scatter_kernel<<<(ET+255)/256, 256, 0, stream>>>(edges, cursor, esrc);

  mm_kernel<128,32><<<(N_NODES+31)/32, 256, 0, stream>>>(x, W1, W1, 128, xp1);
  alpha1_kernel<<<(N_NODES+3)/4, 256, 0, stream>>>(xp1, as1v, ad1v, as1, ad1);
  agg1_kernel  <<<(N_NODES+3)/4, 256, 0, stream>>>(rowptr, esrc, xp1, as1, ad1, b1, h);

  mm_kernel<64,64><<<(N_NODES+63)/64, 256, 0, stream>>>(h, Wmu, Wst, 32, xp2);
  alpha2_kernel<<<(N_NODES+3)/4, 256, 0, stream>>>(xp2, asmu, admu, asst, adst, as2, ad2);
  agg2_kernel  <<<(N_NODES+3)/4, 256, 0, stream>>>(rowptr, esrc, xp2, as2, ad2, bmu, bst, out);
}

// Round 3
// 404.747 us; speedup vs baseline: 1.4274x; 1.1751x over previous
//
#include <hip/hip_runtime.h>
#include <math.h>

#define N_NODES 50000
#define N_EDGES 800000
#define ET (N_EDGES + N_NODES)   // 850000 incl. self-loops
#define KD 128                   // inner dim of both matmuls
#define Z 32
#define NBS ((N_NODES + 1023) / 1024)   // 49 scan blocks

static __device__ __forceinline__ float lrelu(float x){ return x > 0.f ? x : 0.2f*x; }

// ---------- CSR build ----------
__global__ __launch_bounds__(256) void hist_kernel(const int* __restrict__ edges, int* __restrict__ deg){
  int k = blockIdx.x*256 + threadIdx.x;
  if(k >= ET) return;
  int d = (k < N_EDGES) ? edges[N_EDGES + k] : (k - N_EDGES);
  atomicAdd(&deg[d], 1);
}

__global__ __launch_bounds__(256) void scan1_kernel(const int* __restrict__ deg, int* __restrict__ bsum){
  int b = blockIdx.x, t = threadIdx.x;
  int base = b*1024 + t*4;
  int s = 0;
  #pragma unroll
  for(int i=0;i<4;i++){ int n = base+i; if(n < N_NODES) s += deg[n]; }
  for(int off=32; off; off>>=1) s += __shfl_xor(s, off);
  __shared__ int ws[4];
  if((t&63)==0) ws[t>>6] = s;
  __syncthreads();
  if(t==0) bsum[b] = ws[0]+ws[1]+ws[2]+ws[3];
}

__global__ __launch_bounds__(64) void scan2_kernel(const int* __restrict__ bsum, int* __restrict__ bpre){
  int t = threadIdx.x;
  int x = (t < NBS) ? bsum[t] : 0;
  int v = x;
  for(int off=1; off<64; off<<=1){
    int u = __shfl_up(v, off);
    if(t >= off) v += u;
  }
  if(t < NBS) bpre[t] = v - x;
}

__global__ __launch_bounds__(256) void scan3_kernel(const int* __restrict__ deg, const int* __restrict__ bpre,
                                                    int* __restrict__ rowptr, int* __restrict__ cursor){
  int b = blockIdx.x, t = threadIdx.x;
  int lane = t & 63, wv = t >> 6;
  int base = b*1024 + t*4;
  int d[4]; int s = 0;
  #pragma unroll
  for(int i=0;i<4;i++){ int n = base+i; d[i] = (n < N_NODES) ? deg[n] : 0; s += d[i]; }
  int v = s;
  for(int off=1; off<64; off<<=1){
    int u = __shfl_up(v, off);
    if(lane >= off) v += u;
  }
  int texcl = v - s;
  __shared__ int wtot[4];
  if(lane == 63) wtot[wv] = v;
  __syncthreads();
  int woff = 0;
  for(int i=0;i<wv;i++) woff += wtot[i];
  int run = bpre[b] + woff + texcl;
  #pragma unroll
  for(int i=0;i<4;i++){
    int n = base+i;
    if(n < N_NODES){ rowptr[n] = run; cursor[n] = run; run += d[i]; }
  }
  if(b == 0 && t == 0) rowptr[N_NODES] = ET;
}

__global__ __launch_bounds__(256) void scatter_kernel(const int* __restrict__ edges, int* __restrict__ cursor, int* __restrict__ esrc){
  int k = blockIdx.x*256 + threadIdx.x;
  if(k >= ET) return;
  int s, d;
  if(k < N_EDGES){ s = edges[k]; d = edges[N_EDGES+k]; } else { s = d = k - N_EDGES; }
  int pos = atomicAdd(&cursor[d], 1);
  esrc[pos] = s;
}

// ---------- dense matmul ----------
template<int OC, int NR>
__global__ __launch_bounds__(256) void mm_kernel(const float* __restrict__ X,
                                                 const float* __restrict__ Wa,
                                                 const float* __restrict__ Wb, int splitRow,
                                                 float* __restrict__ out){
  constexpr int G  = OC/4;
  constexpr int RG = 256/G;
  static_assert(NR == RG*4, "rows per block mismatch");
  __shared__ __align__(16) float Wl[OC*KD];

  for(int idx = threadIdx.x; idx < OC*KD; idx += 256){
    int j = idx >> 7;
    int k = idx & 127;
    float v = (j < splitRow) ? Wa[j*KD + k] : Wb[(j-splitRow)*KD + k];
    int k4 = k >> 2, u = k & 3;
    Wl[j*KD + 4*(k4 ^ (j & 31)) + u] = v;
  }
  __syncthreads();

  int cx = threadIdx.x % G;
  int ry = threadIdx.x / G;
  int row0 = blockIdx.x * NR + ry*4;

  float acc[4][4];
  #pragma unroll
  for(int i=0;i<4;i++)
    #pragma unroll
    for(int j=0;j<4;j++) acc[i][j] = 0.f;

  for(int k4 = 0; k4 < KD/4; k4++){
    float4 xv[4];
    #pragma unroll
    for(int i=0;i<4;i++){
      int r = row0 + i; r = r < N_NODES ? r : N_NODES-1;
      xv[i] = *(const float4*)(X + (size_t)r*KD + 4*k4);
    }
    #pragma unroll
    for(int jj=0;jj<4;jj++){
      int c = cx + jj*G;
      float4 wv = *(const float4*)(&Wl[c*KD + 4*(k4 ^ (c & 31))]);
      #pragma unroll
      for(int i=0;i<4;i++){
        acc[i][jj] += xv[i].x*wv.x;
        acc[i][jj] += xv[i].y*wv.y;
        acc[i][jj] += xv[i].z*wv.z;
        acc[i][jj] += xv[i].w*wv.w;
      }
    }
  }

  #pragma unroll
  for(int i=0;i<4;i++){
    int r = row0 + i;
    if(r < N_NODES){
      #pragma unroll
      for(int jj=0;jj<4;jj++) out[(size_t)r*OC + cx + jj*G] = acc[i][jj];
    }
  }
}

// ---------- attention coefficient dots ----------
__global__ __launch_bounds__(256) void alpha1_kernel(const float* __restrict__ xp,
                                                     const float* __restrict__ asv, const float* __restrict__ adv,
                                                     float* __restrict__ as1, float* __restrict__ ad1){
  int node = blockIdx.x*4 + (threadIdx.x>>6);
  int l = threadIdx.x & 63;
  if(node >= N_NODES) return;
  float x0 = xp[(size_t)node*128 + l], x1 = xp[(size_t)node*128 + 64 + l];
  float s0 = x0*asv[l], s1 = x1*asv[64+l];
  float d0 = x0*adv[l], d1 = x1*adv[64+l];
  for(int off=32; off; off>>=1){
    s0 += __shfl_xor(s0, off); s1 += __shfl_xor(s1, off);
    d0 += __shfl_xor(d0, off); d1 += __shfl_xor(d1, off);
  }
  if(l == 0){ as1[node*2]=s0; as1[node*2+1]=s1; ad1[node*2]=d0; ad1[node*2+1]=d1; }
}

__global__ __launch_bounds__(256) void alpha2_kernel(const float* __restrict__ xp2,
                                                     const float* __restrict__ asmu, const float* __restrict__ admu,
                                                     const float* __restrict__ asst, const float* __restrict__ adst,
                                                     float* __restrict__ as2, float* __restrict__ ad2){
  int node = blockIdx.x*4 + (threadIdx.x>>6);
  int l = threadIdx.x & 63;
  if(node >= N_NODES) return;
  int half = l >> 5, c = l & 31;
  float v = xp2[(size_t)node*64 + l];
  float sp = v * (half ? asst[c] : asmu[c]);
  float dp = v * (half ? adst[c] : admu[c]);
  for(int off=16; off; off>>=1){ sp += __shfl_xor(sp, off); dp += __shfl_xor(dp, off); }
  if(c == 0){ as2[node*2+half] = sp; ad2[node*2+half] = dp; }
}

// ---------- edge aggregation, layer 1 (one wave per dst; unroll-4 edge loop) ----------
__global__ __launch_bounds__(256) void agg1_kernel(const int* __restrict__ rowptr, const int* __restrict__ esrc,
                                                   const float* __restrict__ xp, const float* __restrict__ as1,
                                                   const float* __restrict__ ad1, const float* __restrict__ b1,
                                                   float* __restrict__ h){
  int node = blockIdx.x*4 + (threadIdx.x>>6);
  int l = threadIdx.x & 63;
  if(node >= N_NODES) return;
  int beg = rowptr[node], end = rowptr[node+1];
  const float2* as1p = (const float2*)as1;
  float2 adn = ((const float2*)ad1)[node];
  // pass 1: segment max per head (lanes partition edges)
  float m0 = -3.4e38f, m1 = -3.4e38f;
  for(int i = beg + l; i < end; i += 64){
    float2 a = as1p[esrc[i]];
    m0 = fmaxf(m0, lrelu(a.x + adn.x));
    m1 = fmaxf(m1, lrelu(a.y + adn.y));
  }
  for(int off=32; off; off>>=1){ m0 = fmaxf(m0, __shfl_xor(m0, off)); m1 = fmaxf(m1, __shfl_xor(m1, off)); }
  // pass 2: unroll-4 for 4 outstanding gathers; lane l holds features 2l,2l+1
  const float2* xpv = (const float2*)xp;
  float accx = 0.f, accy = 0.f, s0 = 0.f, s1 = 0.f;
  int n = end - beg;
  int nq = n & ~3;
  for(int q = 0; q < nq; q += 4){
    int e0 = esrc[beg+q], e1 = esrc[beg+q+1], e2 = esrc[beg+q+2], e3 = esrc[beg+q+3];
    float2 a0 = as1p[e0], a1 = as1p[e1], a2 = as1p[e2], a3 = as1p[e3];
    float2 x0 = xpv[(size_t)e0*64 + l];
    float2 x1 = xpv[(size_t)e1*64 + l];
    float2 x2 = xpv[(size_t)e2*64 + l];
    float2 x3 = xpv[(size_t)e3*64 + l];
    float w00 = __expf(lrelu(a0.x + adn.x) - m0), w01 = __expf(lrelu(a0.y + adn.y) - m1);
    float w10 = __expf(lrelu(a1.x + adn.x) - m0), w11 = __expf(lrelu(a1.y + adn.y) - m1);
    float w20 = __expf(lrelu(a2.x + adn.x) - m0), w21 = __expf(lrelu(a2.y + adn.y) - m1);
    float w30 = __expf(lrelu(a3.x + adn.x) - m0), w31 = __expf(lrelu(a3.y + adn.y) - m1);
    s0 += w00 + w10 + w20 + w30;
    s1 += w01 + w11 + w21 + w31;
    float v0 = (l < 32) ? w00 : w01;
    float v1 = (l < 32) ? w10 : w11;
    float v2 = (l < 32) ? w20 : w21;
    float v3 = (l < 32) ? w30 : w31;
    accx += v0*x0.x + v1*x1.x + v2*x2.x + v3*x3.x;
    accy += v0*x0.y + v1*x1.y + v2*x2.y + v3*x3.y;
  }
  for(int i = beg + nq; i < end; i++){
    int s = esrc[i];
    float2 a = as1p[s];
    float w0 = __expf(lrelu(a.x + adn.x) - m0);
    float w1 = __expf(lrelu(a.y + adn.y) - m1);
    s0 += w0; s1 += w1;
    float2 xv = xpv[(size_t)s*64 + l];
    float w = (l < 32) ? w0 : w1;
    accx += w * xv.x;
    accy += w * xv.y;
  }
  float sd = (l < 32) ? s0 : s1;
  float2 bb = ((const float2*)b1)[l];
  float2 r;
  r.x = fmaxf(accx/sd + bb.x, 0.f);
  r.y = fmaxf(accy/sd + bb.y, 0.f);
  ((float2*)h)[(size_t)node*64 + l] = r;
}

// ---------- edge aggregation, layer 2 (mu+std fused; unroll-4) ----------
__global__ __launch_bounds__(256) void agg2_kernel(const int* __restrict__ rowptr, const int* __restrict__ esrc,
                                                   const float* __restrict__ xp2, const float* __restrict__ as2,
                                                   const float* __restrict__ ad2, const float* __restrict__ bmu,
                                                   const float* __restrict__ bst, float* __restrict__ out){
  int node = blockIdx.x*4 + (threadIdx.x>>6);
  int l = threadIdx.x & 63;
  if(node >= N_NODES) return;
  int half = l >> 5, c = l & 31;
  int beg = rowptr[node], end = rowptr[node+1];
  const float2* as2p = (const float2*)as2;
  float2 adn2 = ((const float2*)ad2)[node];
  float adn = half ? adn2.y : adn2.x;
  float m = -3.4e38f;
  for(int i = beg + c; i < end; i += 32){
    float2 a = as2p[esrc[i]];
    m = fmaxf(m, lrelu((half ? a.y : a.x) + adn));
  }
  for(int off=16; off; off>>=1) m = fmaxf(m, __shfl_xor(m, off));
  float acc = 0.f, ssum = 0.f;
  int n = end - beg;
  int nq = n & ~3;
  for(int q = 0; q < nq; q += 4){
    int e0 = esrc[beg+q], e1 = esrc[beg+q+1], e2 = esrc[beg+q+2], e3 = esrc[beg+q+3];
    float2 a0 = as2p[e0], a1 = as2p[e1], a2 = as2p[e2], a3 = as2p[e3];
    float x0 = xp2[(size_t)e0*64 + l];
    float x1 = xp2[(size_t)e1*64 + l];
    float x2 = xp2[(size_t)e2*64 + l];
    float x3 = xp2[(size_t)e3*64 + l];
    float w0 = __expf(lrelu((half ? a0.y : a0.x) + adn) - m);
    float w1 = __expf(lrelu((half ? a1.y : a1.x) + adn) - m);
    float w2 = __expf(lrelu((half ? a2.y : a2.x) + adn) - m);
    float w3 = __expf(lrelu((half ? a3.y : a3.x) + adn) - m);
    ssum += w0 + w1 + w2 + w3;
    acc  += w0*x0 + w1*x1 + w2*x2 + w3*x3;
  }
  for(int i = beg + nq; i < end; i++){
    int s = esrc[i];
    float2 a = as2p[s];
    float w = __expf(lrelu((half ? a.y : a.x) + adn) - m);
    ssum += w;
    acc += w * xp2[(size_t)s*64 + l];
  }
  float r = acc/ssum + (half ? bst[c] : bmu[c]);
  out[(half ? (size_t)N_NODES*Z : 0) + (size_t)node*Z + c] = r;
}

extern "C" void kernel_launch(void* const* d_in, const int* in_sizes, int n_in,
                              void* d_out, int out_size, void* d_ws, size_t ws_size,
                              hipStream_t stream){
  const float* x    = (const float*)d_in[0];
  const int*   edges= (const int*)d_in[1];
  const float* W1   = (const float*)d_in[2];
  const float* as1v = (const float*)d_in[3];
  const float* ad1v = (const float*)d_in[4];
  const float* b1   = (const float*)d_in[5];
  const float* Wmu  = (const float*)d_in[6];
  const float* asmu = (const float*)d_in[7];
  const float* admu = (const float*)d_in[8];
  const float* bmu  = (const float*)d_in[9];
  const float* Wst  = (const float*)d_in[10];
  const float* asst = (const float*)d_in[11];
  const float* adst = (const float*)d_in[12];
  const float* bst  = (const float*)d_in[13];
  float* out = (float*)d_out;

  char* p = (char*)d_ws;
  auto alloc = [&](size_t bytes)->char*{ char* r = p; p += (bytes + 255) & ~size_t(255); return r; };
  int*   deg    = (int*)  alloc((size_t)N_NODES*4);
  int*   rowptr = (int*)  alloc((size_t)(N_NODES+1)*4);
  int*   cursor = (int*)  alloc((size_t)N_NODES*4);
  int*   esrc   = (int*)  alloc((size_t)ET*4);
  int*   bsum   = (int*)  alloc((size_t)NBS*4);
  int*   bpre   = (int*)  alloc((size_t)NBS*4);
  float* xp1    = (float*)alloc((size_t)N_NODES*128*4);
  float* as1    = (float*)alloc((size_t)N_NODES*2*4);
  float* ad1    = (float*)alloc((size_t)N_NODES*2*4);
  float* h      = (float*)alloc((size_t)N_NODES*128*4);
  float* xp2    = (float*)alloc((size_t)N_NODES*64*4);
  float* as2    = (float*)alloc((size_t)N_NODES*2*4);
  float* ad2    = (float*)alloc((size_t)N_NODES*2*4);

  hipMemsetAsync(deg, 0, (size_t)N_NODES*4, stream);
  hist_kernel   <<<(ET+255)/256, 256, 0, stream>>>(edges, deg);
  scan1_kernel  <<<NBS, 256, 0, stream>>>(deg, bsum);
  scan2_kernel  <<<1, 64, 0, stream>>>(bsum, bpre);
  scan3_kernel  <<<NBS, 256, 0, stream>>>(deg, bpre, rowptr, cursor);
  scatter_kernel<<<(ET+255)/256, 256, 0, stream>>>(edges, cursor, esrc);

  mm_kernel<128,32><<<(N_NODES+31)/32, 256, 0, stream>>>(x, W1, W1, 128, xp1);
  alpha1_kernel<<<(N_NODES+3)/4, 256, 0, stream>>>(xp1, as1v, ad1v, as1, ad1);
  agg1_kernel  <<<(N_NODES+3)/4, 256, 0, stream>>>(rowptr, esrc, xp1, as1, ad1, b1, h);

  mm_kernel<64,64><<<(N_NODES+63)/64, 256, 0, stream>>>(h, Wmu, Wst, 32, xp2);
  alpha2_kernel<<<(N_NODES+3)/4, 256, 0, stream>>>(xp2, asmu, admu, asst, adst, as2, ad2);
  agg2_kernel  <<<(N_NODES+3)/4, 256, 0, stream>>>(rowptr, esrc, xp2, as2, ad2, bmu, bst, out);
}